// Round 1
// baseline (374.608 us; speedup 1.0000x reference)
//
#include <hip/hip_runtime.h>
#include <math.h>

#define M     1024
#define NC    32
#define HF    256
#define WF    256
#define RH    8
#define MAXW  128
#define OUT0  (M * RH * MAXW * NC)   // 33,554,432 floats

struct BoxParam {
    float p1x, p1y;   // top-left corner (already /4)
    float axx, axy;   // per-x step
    float ayx, ayy;   // per-y step
    int   width;      // clipped int width
    int   n;          // feature-map batch index
};

// ---------------------------------------------------------------------------
// Setup: per-box geometry + exact width + stable descending sort by width.
// One block, 1024 threads (one per box).
// ---------------------------------------------------------------------------
__global__ __launch_bounds__(1024) void roi_setup_kernel(
    const float* __restrict__ boxes, const int* __restrict__ mapping,
    BoxParam* __restrict__ params, float* __restrict__ out_tail)
{
    __shared__ int s_w[M];
    const int i = threadIdx.x;

    // boxes/4.0 is exact (power of two)
    float x1 = boxes[i * 8 + 0] * 0.25f, y1 = boxes[i * 8 + 1] * 0.25f;
    float x2 = boxes[i * 8 + 2] * 0.25f, y2 = boxes[i * 8 + 3] * 0.25f;
    float x4 = boxes[i * 8 + 6] * 0.25f, y4 = boxes[i * 8 + 7] * 0.25f;

    float dwx = x2 - x1, dwy = y2 - y1;   // p2 - p1
    float dhx = x4 - x1, dhy = y4 - y1;   // p4 - p1

    // norm() must match numpy bit-exactly: forbid FMA contraction here.
    float bw2   = __fadd_rn(__fmul_rn(dwx, dwx), __fmul_rn(dwy, dwy));
    float bh2   = __fadd_rn(__fmul_rn(dhx, dhx), __fmul_rn(dhy, dhy));
    float box_w = __fsqrt_rn(bw2);
    float box_h = __fsqrt_rn(bh2);

    bool  swp = (box_w <= box_h);
    float bwv = swp ? box_h : box_w;
    float bhv = swp ? box_w : box_h;

    float ratio = __fdiv_rn(__fmul_rn(8.0f, bwv), fmaxf(bhv, 1e-6f));
    float wf    = ceilf(ratio);
    wf = fminf(fmaxf(wf, 1.0f), 128.0f);
    int w = (int)wf;

    s_w[i] = w;
    __syncthreads();

    // Stable descending rank: #(w_j > w_i) + #(w_j == w_i, j < i).
    const int4* sw4 = (const int4*)s_w;
    int rank = 0;
    for (int j4 = 0; j4 < M / 4; ++j4) {
        int4 v = sw4[j4];          // broadcast read — no bank conflicts
        int  j = j4 * 4;
        rank += (v.x > w) || ((v.x == w) && (j + 0 < i));
        rank += (v.y > w) || ((v.y == w) && (j + 1 < i));
        rank += (v.z > w) || ((v.z == w) && (j + 2 < i));
        rank += (v.w > w) || ((v.w == w) && (j + 3 < i));
    }

    BoxParam bp;
    bp.p1x = x1; bp.p1y = y1;
    bp.axx = __fdiv_rn(dwx, wf);  bp.axy = __fdiv_rn(dwy, wf);
    bp.ayx = dhx * 0.125f;        bp.ayy = dhy * 0.125f;   // /HEIGHT exact
    bp.width = w;
    bp.n     = mapping[i];
    params[rank] = bp;

    out_tail[rank]     = wf;        // width[order] as float
    out_tail[M + rank] = (float)i;  // order as float
}

// ---------------------------------------------------------------------------
// Main: one block per (sorted box k, output row y). 256 threads:
// lane = xg*32 + c; 16 x-iterations. Writes coalesced over [x][c].
// ---------------------------------------------------------------------------
__global__ __launch_bounds__(256) void roi_main_kernel(
    const float* __restrict__ fm, const BoxParam* __restrict__ params,
    float* __restrict__ out)
{
    const int k = blockIdx.x >> 3;
    const int y = blockIdx.x & 7;
    const BoxParam bp = params[k];       // block-uniform → scalar loads

    const int c  = threadIdx.x & 31;
    const int xg = threadIdx.x >> 5;     // 0..7

    const float* fmc  = fm + ((size_t)bp.n * NC + c) * (size_t)(HF * WF);
    float*       orow = out + ((size_t)(k * RH + y) * MAXW) * NC + c;

    const float yf = (float)y;
    const float bx = bp.p1x + bp.ayx * yf;
    const float by = bp.p1y + bp.ayy * yf;

    #pragma unroll
    for (int xi = 0; xi < 16; ++xi) {
        const int x = xi * 8 + xg;
        float val = 0.0f;
        if (x < bp.width) {
            float xf = (float)x;
            float sx = bx + bp.axx * xf;
            float sy = by + bp.axy * xf;
            float fx0 = floorf(sx), fy0 = floorf(sy);
            float tx = sx - fx0,    ty = sy - fy0;
            int x0 = (int)fx0, y0 = (int)fy0;
            int x1 = x0 + 1,   y1 = y0 + 1;

            float mx0 = (x0 >= 0 && x0 < WF) ? 1.0f : 0.0f;
            float mx1 = (x1 >= 0 && x1 < WF) ? 1.0f : 0.0f;
            float my0 = (y0 >= 0 && y0 < HF) ? 1.0f : 0.0f;
            float my1 = (y1 >= 0 && y1 < HF) ? 1.0f : 0.0f;
            int xc0 = min(max(x0, 0), WF - 1), xc1 = min(max(x1, 0), WF - 1);
            int yc0 = min(max(y0, 0), HF - 1), yc1 = min(max(y1, 0), HF - 1);

            float v00 = fmc[yc0 * WF + xc0] * (mx0 * my0);
            float v01 = fmc[yc0 * WF + xc1] * (mx1 * my0);
            float v10 = fmc[yc1 * WF + xc0] * (mx0 * my1);
            float v11 = fmc[yc1 * WF + xc1] * (mx1 * my1);

            val = v00 * (1.0f - tx) * (1.0f - ty)
                + v01 * tx          * (1.0f - ty)
                + v10 * (1.0f - tx) * ty
                + v11 * tx          * ty;
        }
        orow[x * NC] = val;   // 0 for x >= width (col_mask), buffer is poisoned
    }
}

// ---------------------------------------------------------------------------
extern "C" void kernel_launch(void* const* d_in, const int* in_sizes, int n_in,
                              void* d_out, int out_size, void* d_ws, size_t ws_size,
                              hipStream_t stream)
{
    const float* fm      = (const float*)d_in[0];
    const float* boxes   = (const float*)d_in[1];
    const int*   mapping = (const int*)d_in[2];
    float*       out     = (float*)d_out;
    BoxParam*    params  = (BoxParam*)d_ws;   // 32 KB used

    roi_setup_kernel<<<1, 1024, 0, stream>>>(boxes, mapping, params, out + OUT0);
    roi_main_kernel<<<M * RH, 256, 0, stream>>>(fm, params, out);
}

// Round 2
// 345.852 us; speedup vs baseline: 1.0831x; 1.0831x over previous
//
#include <hip/hip_runtime.h>
#include <math.h>

#define M     1024
#define NC    32
#define HF    256
#define WF    256
#define RH    8
#define MAXW  128
#define OUT0  (M * RH * MAXW * NC)   // 33,554,432 floats

struct BoxParam {
    float p1x, p1y;   // top-left corner (already /4)
    float axx, axy;   // per-x step
    float ayx, ayy;   // per-y step
    int   width;      // clipped int width
    int   n;          // feature-map batch index
};

// Geometry + exact width (must match numpy bit-exactly: no FMA contraction
// in the norm/ratio path).
__device__ __forceinline__ int box_geom(
    const float* __restrict__ boxes, int i,
    float& x1, float& y1, float& dwx, float& dwy,
    float& dhx, float& dhy, float& wf)
{
    x1 = boxes[i * 8 + 0] * 0.25f; y1 = boxes[i * 8 + 1] * 0.25f;
    float x2 = boxes[i * 8 + 2] * 0.25f, y2 = boxes[i * 8 + 3] * 0.25f;
    float x4 = boxes[i * 8 + 6] * 0.25f, y4 = boxes[i * 8 + 7] * 0.25f;
    dwx = x2 - x1; dwy = y2 - y1;
    dhx = x4 - x1; dhy = y4 - y1;
    float bw2   = __fadd_rn(__fmul_rn(dwx, dwx), __fmul_rn(dwy, dwy));
    float bh2   = __fadd_rn(__fmul_rn(dhx, dhx), __fmul_rn(dhy, dhy));
    float box_w = __fsqrt_rn(bw2);
    float box_h = __fsqrt_rn(bh2);
    bool  swp = (box_w <= box_h);
    float bwv = swp ? box_h : box_w;
    float bhv = swp ? box_w : box_h;
    float ratio = __fdiv_rn(__fmul_rn(8.0f, bwv), fmaxf(bhv, 1e-6f));
    wf = fminf(fmaxf(ceilf(ratio), 1.0f), 128.0f);
    return (int)wf;
}

// ---------------------------------------------------------------------------
// Setup: 16 blocks x 256 threads. Every block computes all 1024 widths
// (redundant, trivial VALU), then block b ranks boxes [b*64, b*64+64) with
// 4 threads per box (each scans a quarter of the widths), shuffle-reduced.
// ---------------------------------------------------------------------------
__global__ __launch_bounds__(256) void roi_setup_kernel(
    const float* __restrict__ boxes, const int* __restrict__ mapping,
    BoxParam* __restrict__ params, float* __restrict__ out_tail)
{
    __shared__ int s_w[M];
    const int t = threadIdx.x, b = blockIdx.x;

    #pragma unroll
    for (int r = 0; r < 4; ++r) {
        int i = r * 256 + t;
        float x1, y1, dwx, dwy, dhx, dhy, wf;
        s_w[i] = box_geom(boxes, i, x1, y1, dwx, dwy, dhx, dhy, wf);
    }
    __syncthreads();

    const int local = t >> 2;        // 0..63: box within this block's slice
    const int q     = t & 3;         // quarter of the width array to scan
    const int i     = b * 64 + local;
    const int w     = s_w[i];

    // Stable descending rank: #(w_j > w_i) + #(w_j == w_i, j < i).
    const int4* sw4 = (const int4*)(s_w + q * 256);
    int rank = 0;
    for (int j4 = 0; j4 < 64; ++j4) {
        int4 v = sw4[j4];
        int  j = q * 256 + j4 * 4;
        rank += (v.x > w) || ((v.x == w) && (j + 0 < i));
        rank += (v.y > w) || ((v.y == w) && (j + 1 < i));
        rank += (v.z > w) || ((v.z == w) && (j + 2 < i));
        rank += (v.w > w) || ((v.w == w) && (j + 3 < i));
    }
    // 4-lane reduce (groups are 4-aligned within the wave)
    rank += __shfl_down(rank, 1);
    rank += __shfl_down(rank, 2);

    if (q == 0) {
        float x1, y1, dwx, dwy, dhx, dhy, wf;
        box_geom(boxes, i, x1, y1, dwx, dwy, dhx, dhy, wf);
        BoxParam bp;
        bp.p1x = x1; bp.p1y = y1;
        bp.axx = __fdiv_rn(dwx, wf);  bp.axy = __fdiv_rn(dwy, wf);
        bp.ayx = dhx * 0.125f;        bp.ayy = dhy * 0.125f;
        bp.width = w;
        bp.n     = mapping[i];
        params[rank] = bp;
        out_tail[rank]     = wf;        // width[order] as float
        out_tail[M + rank] = (float)i;  // order as float
    }
}

// ---------------------------------------------------------------------------
// Main: blockIdx = y*1024 + k  (all 8 rows of box k share blockIdx%8 → same
// XCD under round-robin dispatch → L2 reuse across overlapping rows).
// 256 threads = 8 x-groups x 32 channels. Depth-2 software pipeline keeps
// 8 gathers in flight per wave; weights fold bounds+width masks so the
// inner loop is branch-free (trip count is block-uniform).
// ---------------------------------------------------------------------------
__global__ __launch_bounds__(256) void roi_main_kernel(
    const float* __restrict__ fm, const BoxParam* __restrict__ params,
    float* __restrict__ out)
{
    const int k = blockIdx.x & (M - 1);
    const int y = blockIdx.x >> 10;
    const BoxParam bp = params[k];     // block-uniform → scalar loads

    const int c  = threadIdx.x & 31;
    const int xg = threadIdx.x >> 5;   // 0..7

    const float* fmc  = fm + ((size_t)(bp.n * NC + c)) * (size_t)(HF * WF);
    float*       orow = out + ((size_t)(k * RH + y) * MAXW) * NC + c;

    const float bx = fmaf(bp.ayx, (float)y, bp.p1x);
    const float by = fmaf(bp.ayy, (float)y, bp.p1y);
    const int width = bp.width;
    const int niter = (width + 7) >> 3;   // block-uniform trip count

    // issue: compute masked bilinear weights + fire the 4 gathers
    auto issue = [&](int xi,
                     float& u00, float& u01, float& u10, float& u11,
                     float& q00, float& q01, float& q10, float& q11) {
        const int x = xi * 8 + xg;
        float xf = (float)x;
        float sx = fmaf(bp.axx, xf, bx);
        float sy = fmaf(bp.axy, xf, by);
        float fx0 = floorf(sx), fy0 = floorf(sy);
        float tx = sx - fx0,    ty = sy - fy0;
        int x0 = (int)fx0, y0 = (int)fy0;
        int x1 = x0 + 1,   y1 = y0 + 1;
        float valid = (x < width) ? 1.0f : 0.0f;
        float mx0 = (x0 >= 0 && x0 < WF) ? valid : 0.0f;
        float mx1 = (x1 >= 0 && x1 < WF) ? valid : 0.0f;
        float my0 = (y0 >= 0 && y0 < HF) ? 1.0f : 0.0f;
        float my1 = (y1 >= 0 && y1 < HF) ? 1.0f : 0.0f;
        int xc0 = min(max(x0, 0), WF - 1), xc1 = min(max(x1, 0), WF - 1);
        int yc0 = min(max(y0, 0), HF - 1), yc1 = min(max(y1, 0), HF - 1);
        float omtx = 1.0f - tx, omty = 1.0f - ty;
        q00 = omtx * omty * (mx0 * my0);
        q01 = tx   * omty * (mx1 * my0);
        q10 = omtx * ty   * (mx0 * my1);
        q11 = tx   * ty   * (mx1 * my1);
        const float* r0 = fmc + yc0 * WF;
        const float* r1 = fmc + yc1 * WF;
        u00 = r0[xc0]; u01 = r0[xc1];
        u10 = r1[xc0]; u11 = r1[xc1];
    };
    auto consume = [&](int xi,
                       float u00, float u01, float u10, float u11,
                       float q00, float q01, float q10, float q11) {
        float val = u00 * q00 + u01 * q01 + u10 * q10 + u11 * q11;
        orow[(size_t)((xi * 8 + xg) * NC)] = val;
    };

    // Two named stages (A/B) — no dynamically-indexed arrays → no scratch.
    float a00, a01, a10, a11, pa00, pa01, pa10, pa11;
    float b00, b01, b10, b11, pb00, pb01, pb10, pb11;

    issue(0, a00, a01, a10, a11, pa00, pa01, pa10, pa11);
    if (niter > 1) issue(1, b00, b01, b10, b11, pb00, pb01, pb10, pb11);

    int i = 0;
    for (; i + 2 < niter; i += 2) {
        consume(i, a00, a01, a10, a11, pa00, pa01, pa10, pa11);
        issue(i + 2, a00, a01, a10, a11, pa00, pa01, pa10, pa11);
        if (i + 3 < niter)
            issue(i + 3, b00, b01, b10, b11, pb00, pb01, pb10, pb11);
        consume(i + 1, b00, b01, b10, b11, pb00, pb01, pb10, pb11);
        if (i + 3 < niter) {
            // rotate: freshly issued (i+3) is in B, next loop's i+1 reads B — ok
        }
    }
    // tail: 1 or 2 iterations remain
    consume(i, a00, a01, a10, a11, pa00, pa01, pa10, pa11);
    if (i + 1 < niter)
        consume(i + 1, b00, b01, b10, b11, pb00, pb01, pb10, pb11);

    // zero-fill x >= ceil(width/8)*8 (col_mask; d_out is poisoned each launch)
    for (int xi = niter; xi < 16; ++xi)
        orow[(size_t)((xi * 8 + xg) * NC)] = 0.0f;
}

// ---------------------------------------------------------------------------
extern "C" void kernel_launch(void* const* d_in, const int* in_sizes, int n_in,
                              void* d_out, int out_size, void* d_ws, size_t ws_size,
                              hipStream_t stream)
{
    const float* fm      = (const float*)d_in[0];
    const float* boxes   = (const float*)d_in[1];
    const int*   mapping = (const int*)d_in[2];
    float*       out     = (float*)d_out;
    BoxParam*    params  = (BoxParam*)d_ws;   // 32 KB used

    roi_setup_kernel<<<16, 256, 0, stream>>>(boxes, mapping, params, out + OUT0);
    roi_main_kernel<<<M * RH, 256, 0, stream>>>(fm, params, out);
}

// Round 3
// 303.157 us; speedup vs baseline: 1.2357x; 1.1408x over previous
//
#include <hip/hip_runtime.h>
#include <math.h>

#define M     1024
#define NB    16
#define NC    32
#define HF    256
#define WF    256
#define RH    8
#define MAXW  128
#define OUT0  (M * RH * MAXW * NC)   // 33,554,432 floats

struct BoxParam {
    float p1x, p1y;   // top-left corner (already /4)
    float axx, axy;   // per-x step
    float ayx, ayy;   // per-y step
    int   width;      // clipped int width
    int   n;          // feature-map batch index
};

// Geometry + exact width (must match numpy bit-exactly: no FMA contraction).
__device__ __forceinline__ int box_geom(
    const float* __restrict__ boxes, int i,
    float& x1, float& y1, float& dwx, float& dwy,
    float& dhx, float& dhy, float& wf)
{
    x1 = boxes[i * 8 + 0] * 0.25f; y1 = boxes[i * 8 + 1] * 0.25f;
    float x2 = boxes[i * 8 + 2] * 0.25f, y2 = boxes[i * 8 + 3] * 0.25f;
    float x4 = boxes[i * 8 + 6] * 0.25f, y4 = boxes[i * 8 + 7] * 0.25f;
    dwx = x2 - x1; dwy = y2 - y1;
    dhx = x4 - x1; dhy = y4 - y1;
    float bw2   = __fadd_rn(__fmul_rn(dwx, dwx), __fmul_rn(dwy, dwy));
    float bh2   = __fadd_rn(__fmul_rn(dhx, dhx), __fmul_rn(dhy, dhy));
    float box_w = __fsqrt_rn(bw2);
    float box_h = __fsqrt_rn(bh2);
    bool  swp = (box_w <= box_h);
    float bwv = swp ? box_h : box_w;
    float bhv = swp ? box_w : box_h;
    float ratio = __fdiv_rn(__fmul_rn(8.0f, bwv), fmaxf(bhv, 1e-6f));
    wf = fminf(fmaxf(ceilf(ratio), 1.0f), 128.0f);
    return (int)wf;
}

// ---------------------------------------------------------------------------
// Setup: 16 blocks x 256 threads; block b ranks boxes [b*64, b*64+64) with
// 4 threads per box, shuffle-reduced. Stable descending sort by width.
// ---------------------------------------------------------------------------
__global__ __launch_bounds__(256) void roi_setup_kernel(
    const float* __restrict__ boxes, const int* __restrict__ mapping,
    BoxParam* __restrict__ params, float* __restrict__ out_tail)
{
    __shared__ int s_w[M];
    const int t = threadIdx.x, b = blockIdx.x;

    #pragma unroll
    for (int r = 0; r < 4; ++r) {
        int i = r * 256 + t;
        float x1, y1, dwx, dwy, dhx, dhy, wf;
        s_w[i] = box_geom(boxes, i, x1, y1, dwx, dwy, dhx, dhy, wf);
    }
    __syncthreads();

    const int local = t >> 2;
    const int q     = t & 3;
    const int i     = b * 64 + local;
    const int w     = s_w[i];

    const int4* sw4 = (const int4*)(s_w + q * 256);
    int rank = 0;
    for (int j4 = 0; j4 < 64; ++j4) {
        int4 v = sw4[j4];
        int  j = q * 256 + j4 * 4;
        rank += (v.x > w) || ((v.x == w) && (j + 0 < i));
        rank += (v.y > w) || ((v.y == w) && (j + 1 < i));
        rank += (v.z > w) || ((v.z == w) && (j + 2 < i));
        rank += (v.w > w) || ((v.w == w) && (j + 3 < i));
    }
    rank += __shfl_down(rank, 1);
    rank += __shfl_down(rank, 2);

    if (q == 0) {
        float x1, y1, dwx, dwy, dhx, dhy, wf;
        box_geom(boxes, i, x1, y1, dwx, dwy, dhx, dhy, wf);
        BoxParam bp;
        bp.p1x = x1; bp.p1y = y1;
        bp.axx = __fdiv_rn(dwx, wf);  bp.axy = __fdiv_rn(dwy, wf);
        bp.ayx = dhx * 0.125f;        bp.ayy = dhy * 0.125f;
        bp.width = w;
        bp.n     = mapping[i];
        params[rank] = bp;
        out_tail[rank]     = wf;
        out_tail[M + rank] = (float)i;
    }
}

// ---------------------------------------------------------------------------
// Transpose NCHW -> NHWC via LDS tile. Block = (n, y, 64-wide x-tile).
// tile[64][33]: write phase 2-way bank aliasing (free), read phase 2-way.
// ---------------------------------------------------------------------------
__global__ __launch_bounds__(256) void roi_transpose_kernel(
    const float* __restrict__ fm, float* __restrict__ fmT)
{
    __shared__ float tile[64][33];
    const int t  = threadIdx.x;
    const int xb = (blockIdx.x & 3) * 64;
    const int y  = (blockIdx.x >> 2) & (HF - 1);
    const int n  = blockIdx.x >> 10;

    const int c  = t >> 3;
    const int ws = t & 7;
    const float* src = fm + (((size_t)(n * NC + c) * HF + y) * WF + xb + ws * 8);
    float4 v0 = ((const float4*)src)[0];
    float4 v1 = ((const float4*)src)[1];
    const int x0 = ws * 8;
    tile[x0+0][c]=v0.x; tile[x0+1][c]=v0.y; tile[x0+2][c]=v0.z; tile[x0+3][c]=v0.w;
    tile[x0+4][c]=v1.x; tile[x0+5][c]=v1.y; tile[x0+6][c]=v1.z; tile[x0+7][c]=v1.w;
    __syncthreads();

    const int xl = t >> 2;
    const int c0 = (t & 3) * 8;
    float* dst = fmT + (((size_t)(n * HF + y) * WF + xb + xl) * NC + c0);
    float4 w0 = make_float4(tile[xl][c0+0], tile[xl][c0+1], tile[xl][c0+2], tile[xl][c0+3]);
    float4 w1 = make_float4(tile[xl][c0+4], tile[xl][c0+5], tile[xl][c0+6], tile[xl][c0+7]);
    ((float4*)dst)[0] = w0;
    ((float4*)dst)[1] = w1;
}

// ---------------------------------------------------------------------------
// Main (NHWC): block = (k,y) via blockIdx = y*1024+k (rows of one box share
// XCD). 256 threads = 32 x-positions x 8 channel-quads; float4 gathers are
// 128B-contiguous per pixel -> ~2-8 lines per wave load instead of 64.
// sx/sy bit-exact to numpy: (p1 + ax*x) + ay*y, no FMA contraction.
// ---------------------------------------------------------------------------
__global__ __launch_bounds__(256) void roi_main_nhwc(
    const float* __restrict__ fmT, const BoxParam* __restrict__ params,
    float* __restrict__ out)
{
    const int k = blockIdx.x & (M - 1);
    const int y = blockIdx.x >> 10;
    const BoxParam bp = params[k];     // block-uniform -> scalar loads

    const int t  = threadIdx.x;
    const int cg = (t & 7) * 4;        // channel quad
    const int xl = t >> 3;             // 0..31

    const float* fmb  = fmT + (size_t)bp.n * (HF * WF * NC);
    float*       orow = out + ((size_t)(k * RH + y) * MAXW) * NC + cg;

    const float yf    = (float)y;
    const int   width = bp.width;
    const int   niter = (width + 31) >> 5;   // block-uniform trip count

    const float ayxy = __fmul_rn(bp.ayx, yf);
    const float ayyy = __fmul_rn(bp.ayy, yf);

    for (int xi = 0; xi < niter; ++xi) {
        const int x = xi * 32 + xl;
        float xf = (float)x;
        // numpy order: (p1 + ax*x) + ay*y, each op round-to-nearest
        float sx = __fadd_rn(__fadd_rn(bp.p1x, __fmul_rn(bp.axx, xf)), ayxy);
        float sy = __fadd_rn(__fadd_rn(bp.p1y, __fmul_rn(bp.axy, xf)), ayyy);
        float fx0 = floorf(sx), fy0 = floorf(sy);
        float tx = sx - fx0,    ty = sy - fy0;
        int ix0 = (int)fx0, iy0 = (int)fy0;
        int ix1 = ix0 + 1,  iy1 = iy0 + 1;

        float valid = (x < width) ? 1.0f : 0.0f;
        float mx0 = (ix0 >= 0 && ix0 < WF) ? valid : 0.0f;
        float mx1 = (ix1 >= 0 && ix1 < WF) ? valid : 0.0f;
        float my0 = (iy0 >= 0 && iy0 < HF) ? 1.0f : 0.0f;
        float my1 = (iy1 >= 0 && iy1 < HF) ? 1.0f : 0.0f;
        int xc0 = min(max(ix0, 0), WF - 1), xc1 = min(max(ix1, 0), WF - 1);
        int yc0 = min(max(iy0, 0), HF - 1), yc1 = min(max(iy1, 0), HF - 1);

        float omtx = 1.0f - tx, omty = 1.0f - ty;
        float q00 = omtx * omty * (mx0 * my0);
        float q01 = tx   * omty * (mx1 * my0);
        float q10 = omtx * ty   * (mx0 * my1);
        float q11 = tx   * ty   * (mx1 * my1);

        float4 v00 = *(const float4*)(fmb + (size_t)(yc0 * WF + xc0) * NC + cg);
        float4 v01 = *(const float4*)(fmb + (size_t)(yc0 * WF + xc1) * NC + cg);
        float4 v10 = *(const float4*)(fmb + (size_t)(yc1 * WF + xc0) * NC + cg);
        float4 v11 = *(const float4*)(fmb + (size_t)(yc1 * WF + xc1) * NC + cg);

        float4 r;
        r.x = v00.x * q00 + v01.x * q01 + v10.x * q10 + v11.x * q11;
        r.y = v00.y * q00 + v01.y * q01 + v10.y * q10 + v11.y * q11;
        r.z = v00.z * q00 + v01.z * q01 + v10.z * q10 + v11.z * q11;
        r.w = v00.w * q00 + v01.w * q01 + v10.w * q10 + v11.w * q11;
        *(float4*)(orow + (size_t)x * NC) = r;
    }
    // zero-fill remaining columns (col_mask; d_out is poisoned each launch)
    for (int xi = niter; xi < MAXW / 32; ++xi) {
        const int x = xi * 32 + xl;
        *(float4*)(orow + (size_t)x * NC) = make_float4(0.f, 0.f, 0.f, 0.f);
    }
}

// ---------------------------------------------------------------------------
// Fallback (NCHW direct gather) if d_ws can't hold the transposed map.
// ---------------------------------------------------------------------------
__global__ __launch_bounds__(256) void roi_main_nchw(
    const float* __restrict__ fm, const BoxParam* __restrict__ params,
    float* __restrict__ out)
{
    const int k = blockIdx.x & (M - 1);
    const int y = blockIdx.x >> 10;
    const BoxParam bp = params[k];

    const int c  = threadIdx.x & 31;
    const int xg = threadIdx.x >> 5;

    const float* fmc  = fm + ((size_t)(bp.n * NC + c)) * (size_t)(HF * WF);
    float*       orow = out + ((size_t)(k * RH + y) * MAXW) * NC + c;

    const float yf = (float)y;
    const float ayxy = __fmul_rn(bp.ayx, yf);
    const float ayyy = __fmul_rn(bp.ayy, yf);
    const int width = bp.width;
    const int niter = (width + 7) >> 3;

    for (int xi = 0; xi < niter; ++xi) {
        const int x = xi * 8 + xg;
        float xf = (float)x;
        float sx = __fadd_rn(__fadd_rn(bp.p1x, __fmul_rn(bp.axx, xf)), ayxy);
        float sy = __fadd_rn(__fadd_rn(bp.p1y, __fmul_rn(bp.axy, xf)), ayyy);
        float fx0 = floorf(sx), fy0 = floorf(sy);
        float tx = sx - fx0,    ty = sy - fy0;
        int ix0 = (int)fx0, iy0 = (int)fy0;
        int ix1 = ix0 + 1,  iy1 = iy0 + 1;
        float valid = (x < width) ? 1.0f : 0.0f;
        float mx0 = (ix0 >= 0 && ix0 < WF) ? valid : 0.0f;
        float mx1 = (ix1 >= 0 && ix1 < WF) ? valid : 0.0f;
        float my0 = (iy0 >= 0 && iy0 < HF) ? 1.0f : 0.0f;
        float my1 = (iy1 >= 0 && iy1 < HF) ? 1.0f : 0.0f;
        int xc0 = min(max(ix0, 0), WF - 1), xc1 = min(max(ix1, 0), WF - 1);
        int yc0 = min(max(iy0, 0), HF - 1), yc1 = min(max(iy1, 0), HF - 1);
        float omtx = 1.0f - tx, omty = 1.0f - ty;
        float q00 = omtx * omty * (mx0 * my0);
        float q01 = tx   * omty * (mx1 * my0);
        float q10 = omtx * ty   * (mx0 * my1);
        float q11 = tx   * ty   * (mx1 * my1);
        float val = fmc[yc0 * WF + xc0] * q00 + fmc[yc0 * WF + xc1] * q01
                  + fmc[yc1 * WF + xc0] * q10 + fmc[yc1 * WF + xc1] * q11;
        orow[(size_t)(x * NC)] = val;
    }
    for (int xi = niter; xi < 16; ++xi)
        orow[(size_t)((xi * 8 + xg) * NC)] = 0.0f;
}

// ---------------------------------------------------------------------------
extern "C" void kernel_launch(void* const* d_in, const int* in_sizes, int n_in,
                              void* d_out, int out_size, void* d_ws, size_t ws_size,
                              hipStream_t stream)
{
    const float* fm      = (const float*)d_in[0];
    const float* boxes   = (const float*)d_in[1];
    const int*   mapping = (const int*)d_in[2];
    float*       out     = (float*)d_out;

    BoxParam* params = (BoxParam*)d_ws;                       // 32 KB
    const size_t FMT_OFF = 65536;
    const size_t need = FMT_OFF + (size_t)NB * HF * WF * NC * sizeof(float);

    roi_setup_kernel<<<16, 256, 0, stream>>>(boxes, mapping, params, out + OUT0);

    if (ws_size >= need) {
        float* fmT = (float*)((char*)d_ws + FMT_OFF);
        roi_transpose_kernel<<<NB * HF * (WF / 64), 256, 0, stream>>>(fm, fmT);
        roi_main_nhwc<<<M * RH, 256, 0, stream>>>(fmT, params, out);
    } else {
        roi_main_nchw<<<M * RH, 256, 0, stream>>>(fm, params, out);
    }
}